// Round 3
// baseline (191.368 us; speedup 1.0000x reference)
//
#include <hip/hip_runtime.h>
#include <hip/hip_bf16.h>
#include <stdint.h>

#define BATCH 64
#define CIN   64
#define LEN   4096
#define COUT  128
#define KW    7
#define LPOOL 2048
#define NT    4     // l sub-tiles of 64 per block
#define RROWS 72    // sign rows: p = l0-4+r, r in [0,72)
#define RAWP  80    // raw floats per ci row: p = l0-8+col, col in [0,80)
#define SPITCH 64   // ushorts per stg row = 128B (XOR-swizzled by (r&7)<<4 bytes)

typedef __bf16 v8bf __attribute__((ext_vector_type(8)));
typedef unsigned short v8us __attribute__((ext_vector_type(8)));
typedef float  v4f  __attribute__((ext_vector_type(4)));

typedef const __attribute__((address_space(1))) void* gp1_t;
typedef __attribute__((address_space(3))) void* lp3_t;

// Convert conv_w [COUT][CIN][KW] fp32 -> Wt [KW][COUT][CIN] bf16 (RNE).
__global__ __launch_bounds__(256)
void wconv_kernel(const float* __restrict__ W, ushort* __restrict__ Wt) {
    int i = blockIdx.x * 256 + threadIdx.x;
    if (i >= COUT * CIN * KW) return;
    int co  = i / (CIN * KW);
    int rem = i - co * (CIN * KW);
    int ci  = rem / KW;
    int k   = rem - ci * KW;
    uint u = __float_as_uint(W[i]);
    uint r = (u + 0x7FFFu + ((u >> 16) & 1u)) >> 16;   // RNE to bf16
    Wt[(k * COUT + co) * CIN + ci] = (ushort)r;
}

// lgkm-only barrier: LDS producer->consumer visibility WITHOUT draining
// vmcnt (stores / async DMA stay in flight across it). Safe because the
// only cross-wave dependency in the loop is stg (LDS ds_write -> ds_read);
// raw is wave-private (own-wave DMA, own-wave reads).
static __device__ __forceinline__ void sync_lds() {
    asm volatile("s_waitcnt lgkmcnt(0)" ::: "memory");
    __builtin_amdgcn_s_barrier();
}
static __device__ __forceinline__ void wait_vm0() {
    asm volatile("s_waitcnt vmcnt(0)" ::: "memory");
}

// Fused: BN -> sign -> conv (bf16 MFMA) -> alpha -> PReLU -> maxpool2.
// R3 — R2 de-lockstep structure with two correctness fixes:
//  (bugfix A) startup issued DMA(0) and DMA(1) into the SAME raw region
//      before binarize(0) read it -> tile-0 signs came from tile-1 data.
//      Now: DMA(0) | wait | binarize(0) | DMA(1). Invariant: at most ONE
//      outstanding DMA per wave-private raw region, always consumed before
//      the next is issued (the loop already preserves this).
//  (bugfix B) global_load_lds LDS dest must be WAVE-UNIFORM (m104/m108:
//      HW uses uniform base + lane*16; with boundary-masked lanes a
//      per-lane pointer shifts the whole write). Pointer is rawb+i*256,
//      no lane term.
// De-lockstep design (unchanged from R2):
//  (1) wave-private DMA: wave w stages only its 16 ci rows; binarize
//      lanes read only those -> intra-wave vmcnt(0), no barrier for raw.
//  (2) stg double-buffered -> ONE lgkm-only s_barrier per t; no barrier
//      ever drains vmcnt (stores/DMA stay in flight across it).
//  (3) per t: kloop(t) | pool | wait_vm0+binarize(t+1) | DMA(t+2) |
//      stores(t) | lgkm-barrier.
// Numerics identical to R1 (same fma order, sign rule, pooling).
__global__ __launch_bounds__(256, 3)
void conv_kernel(const float* __restrict__ I,
                 const float* __restrict__ bn_g, const float* __restrict__ bn_b,
                 const float* __restrict__ bn_m, const float* __restrict__ bn_v,
                 const ushort* __restrict__ Wt,
                 const float* __restrict__ alpha, const float* __restrict__ prelu,
                 float* __restrict__ out) {
    __shared__ __attribute__((aligned(16))) float  raw[CIN * RAWP];        // 20480 B, wave-private quarters
    __shared__ __attribute__((aligned(16))) ushort stg[2][RROWS * SPITCH]; // 2 x 9216 B

    int tid = threadIdx.x;
    int lane = tid & 63, wave = tid >> 6;
    int b = blockIdx.y, bx = blockIdx.x;
    int l0base = bx * (64 * NT);

    const float* Ib = I + (size_t)b * CIN * LEN;

    // Wave-private DMA plan: wave w owns ci [16w, 16w+16) = 320 float4
    // chunks = 5 slots x 64 lanes. Chunk m = i*64+lane = ci_local*20 + c
    // lands at rawb float m*4 (HW: uniform base rawb+i*256 + lane*16B);
    // global p = l0-8+4c+(0..3).
    float* rawb = raw + wave * 1280;
    const char* gb[5]; int cb[5];
    #pragma unroll
    for (int i = 0; i < 5; ++i) {
        int m = i * 64 + lane;
        int cil = m / 20;
        int c   = m - 20 * cil;
        cb[i] = 16 * c - 32;                                  // byte offset before +4*l0
        gb[i] = (const char*)(Ib + (size_t)(16 * wave + cil) * LEN) + cb[i];
    }

    auto dma_tile = [&](int l0t) {
        int l4 = 4 * l0t;
        #pragma unroll
        for (int i = 0; i < 5; ++i) {
            int off = cb[i] + l4;
            if (off >= 0 && off + 16 <= LEN * 4)
                __builtin_amdgcn_global_load_lds((gp1_t)(gb[i] + l4),
                                                 (lp3_t)(rawb + i * 256), 16, 0, 0);
        }
    };

    dma_tile(l0base);            // DMA(0) only — raw is single-buffered!

    // ---- per-lane BN consts (t-invariant): lanes<36 of each wave handle
    // the wave's two ci-octets (g8 = 2*wave + (lane&1)) at row-quad lane>>1.
    int oc  = lane & 1;
    int brq = lane >> 1;              // 0..17 for lanes 0..35
    int g8  = 2 * wave + oc;
    float sc[8], mn[8], bt[8];
    if (lane < 36) {
        #pragma unroll
        for (int c = 0; c < 8; ++c) {
            int ci = 8 * g8 + c;
            // bit-exact vs np fp32: gamma / sqrt(var + eps)
            sc[c] = __fdiv_rn(bn_g[ci], __fsqrt_rn(__fadd_rn(bn_v[ci], 1e-5f)));
            mn[c] = bn_m[ci];
            bt[c] = bn_b[ci];
        }
    }

    int quad = lane >> 4, lr = lane & 15;
    int cout0 = wave * 32;
    const ushort* wbase = Wt + ((size_t)cout0 + lr) * CIN + quad * 8;
    float pw  = prelu[0];
    float al0 = alpha[cout0 + lr];
    float al1 = alpha[cout0 + 16 + lr];
    float* obase = out + ((size_t)b * COUT) * LPOOL + bx * (32 * NT);

    // W k=0 preload (t-invariant; rotation keeps steady state across t)
    v8bf c00 = *(const v8bf*)(wbase);
    v8bf c01 = *(const v8bf*)(wbase + 16 * CIN);
    v8bf c10 = *(const v8bf*)(wbase + 32);
    v8bf c11 = *(const v8bf*)(wbase + 32 + 16 * CIN);

    // binarize(tile): wave-private raw -> stg[buf]. Caller guarantees this
    // wave's DMA for the tile has drained (wait_vm0) before calling.
    auto binarize = [&](int l0t, int buf) {
        if (lane < 36) {
            const float4* r4 = (const float4*)rawb;
            float4 fr[8];
            #pragma unroll
            for (int c = 0; c < 8; ++c)
                fr[c] = r4[(8 * oc + c) * 20 + brq + 1];
            ushort* sb = &stg[buf][0];
            #pragma unroll
            for (int j = 0; j < 4; ++j) {
                int r = 4 * brq + j;
                int p = l0t - 4 + r;
                bool pok = (p >= 0) && (p < LEN);
                v8us u;
                #pragma unroll
                for (int c = 0; c < 8; ++c) {
                    float v = ((const float*)&fr[c])[j];
                    // (v - mean) * scale + beta, exact np rounding (sign boundary)
                    float x = __fadd_rn(__fmul_rn(__fsub_rn(v, mn[c]), sc[c]), bt[c]);
                    ushort s = x > 0.f ? (ushort)0x3F80 : (x < 0.f ? (ushort)0xBF80 : (ushort)0);
                    u[c] = pok ? s : (ushort)0;
                }
                *(v8us*)(&sb[r * SPITCH + ((g8 ^ (r & 7)) << 3)]) = u;
            }
        }
    };

    wait_vm0();                 // own DMA(0) landed (W/const loads too)
    binarize(l0base, 0);        // consume raw(0)
    if (NT > 1) dma_tile(l0base + 64);   // DMA(1): raw free again
    sync_lds();                 // stg[0] visible to all waves

    for (int t = 0; t < NT; ++t) {
        int l0 = l0base + t * 64;
        const ushort* sb_cur = &stg[t & 1][0];

        // ---- MFMA(t): k-loop unroll 1, W double-buffered in regs ----
        v4f acc[4][2];
        #pragma unroll
        for (int mt = 0; mt < 4; ++mt) { acc[mt][0] = (v4f)0.f; acc[mt][1] = (v4f)0.f; }

        #pragma unroll 1
        for (int k = 0; k < KW; ++k) {
            // prefetch next tap's W (k=6 wraps to k=0 for next t)
            int nk = (k == KW - 1) ? 0 : k + 1;
            const ushort* wn = wbase + nk * COUT * CIN;
            v8bf n00 = *(const v8bf*)(wn);
            v8bf n01 = *(const v8bf*)(wn + 16 * CIN);
            v8bf n10 = *(const v8bf*)(wn + 32);
            v8bf n11 = *(const v8bf*)(wn + 32 + 16 * CIN);

            // A row for output l=mt*16+lr at tap k: r = l + k + 1; (r&7) mt-invariant
            int rk = lr + 1 + k;
            int s8 = rk & 7;
            const ushort* a0p = &sb_cur[rk * SPITCH + ((quad ^ s8) << 3)];        // ci 0..31
            const ushort* a1p = &sb_cur[rk * SPITCH + (((quad ^ 4) ^ s8) << 3)];  // ci 32..63
            #pragma unroll
            for (int mt = 0; mt < 4; ++mt) {
                v8bf a0 = *(const v8bf*)(a0p + mt * 16 * SPITCH);
                v8bf a1 = *(const v8bf*)(a1p + mt * 16 * SPITCH);
                acc[mt][0] = __builtin_amdgcn_mfma_f32_16x16x32_bf16(a0, c00, acc[mt][0], 0, 0, 0);
                acc[mt][1] = __builtin_amdgcn_mfma_f32_16x16x32_bf16(a0, c01, acc[mt][1], 0, 0, 0);
                acc[mt][0] = __builtin_amdgcn_mfma_f32_16x16x32_bf16(a1, c10, acc[mt][0], 0, 0, 0);
                acc[mt][1] = __builtin_amdgcn_mfma_f32_16x16x32_bf16(a1, c11, acc[mt][1], 0, 0, 0);
            }
            c00 = n00; c01 = n01; c10 = n10; c11 = n11;   // rotate
        }

        // ---- pool-compute: acc (32 regs) -> pooled pv (16 regs), acc dies ----
        float pv[2][4][2];
        #pragma unroll
        for (int n2 = 0; n2 < 2; ++n2) {
            float al = n2 ? al1 : al0;
            #pragma unroll
            for (int mt = 0; mt < 4; ++mt) {
                float v0 = acc[mt][n2][0] * al; v0 = v0 > 0.f ? v0 : pw * v0;
                float v1 = acc[mt][n2][1] * al; v1 = v1 > 0.f ? v1 : pw * v1;
                float v2 = acc[mt][n2][2] * al; v2 = v2 > 0.f ? v2 : pw * v2;
                float v3 = acc[mt][n2][3] * al; v3 = v3 > 0.f ? v3 : pw * v3;
                pv[n2][mt][0] = fmaxf(v0, v1);
                pv[n2][mt][1] = fmaxf(v2, v3);
            }
        }

        // ---- binarize(t+1): own DMA(t+1) is >=1 phase old -> vmcnt(0) ~free;
        //      then (and only then) launch DMA(t+2) into the freed raw. ----
        if (t + 1 < NT) {
            wait_vm0();
            binarize(l0 + 64, (t + 1) & 1);
        }
        if (t + 2 < NT) dma_tile(l0 + 128);   // ~2 phases of flight

        // ---- stores(t): issued last, drain under next k-loop ----
        float* ob = obase + t * 32;
        #pragma unroll
        for (int n2 = 0; n2 < 2; ++n2) {
            int co = cout0 + n2 * 16 + lr;
            float* ocp = ob + (size_t)co * LPOOL + quad * 2;
            #pragma unroll
            for (int mt = 0; mt < 4; ++mt)
                *(float2*)(ocp + mt * 8) = make_float2(pv[n2][mt][0], pv[n2][mt][1]);
        }

        sync_lds();   // lgkm-only: stg[nb] visible; stores/DMA stay in flight
    }
}

extern "C" void kernel_launch(void* const* d_in, const int* in_sizes, int n_in,
                              void* d_out, int out_size, void* d_ws, size_t ws_size,
                              hipStream_t stream) {
    const float* I      = (const float*)d_in[0];
    const float* bn_g   = (const float*)d_in[1];
    const float* bn_b   = (const float*)d_in[2];
    const float* bn_m   = (const float*)d_in[3];
    const float* bn_v   = (const float*)d_in[4];
    const float* conv_w = (const float*)d_in[5];
    const float* alpha  = (const float*)d_in[6];
    const float* prelu  = (const float*)d_in[7];
    float* out = (float*)d_out;

    ushort* Wt = (ushort*)d_ws;   // 7*128*64*2 = 114688 bytes

    wconv_kernel<<<(COUT * CIN * KW + 255) / 256, 256, 0, stream>>>(conv_w, Wt);
    dim3 grid(LEN / (64 * NT), BATCH);
    conv_kernel<<<grid, 256, 0, stream>>>(I, bn_g, bn_b, bn_m, bn_v, Wt, alpha, prelu, out);
}

// Round 5
// 179.369 us; speedup vs baseline: 1.0669x; 1.0669x over previous
//
#include <hip/hip_runtime.h>
#include <hip/hip_bf16.h>
#include <stdint.h>

#define BATCH 64
#define CIN   64
#define LEN   4096
#define COUT  128
#define KW    7
#define LPOOL 2048
#define NT    2     // R4: l sub-tiles of 64 per block (was 4) -> grid 2048 = 8 blocks/CU
#define RROWS 72    // sign rows: p = l0-4+r, r in [0,72)
#define RAWP  80    // raw floats per ci row: p = l0-8+col, col in [0,80)
#define SPITCH 64   // ushorts per stg row = 128B (XOR-swizzled by (r&7)<<4 bytes)

typedef __bf16 v8bf __attribute__((ext_vector_type(8)));
typedef unsigned short v8us __attribute__((ext_vector_type(8)));
typedef float  v4f  __attribute__((ext_vector_type(4)));

typedef const __attribute__((address_space(1))) void* gp1_t;
typedef __attribute__((address_space(3))) void* lp3_t;

// Convert conv_w [COUT][CIN][KW] fp32 -> Wt [KW][COUT][CIN] bf16 (RNE).
__global__ __launch_bounds__(256)
void wconv_kernel(const float* __restrict__ W, ushort* __restrict__ Wt) {
    int i = blockIdx.x * 256 + threadIdx.x;
    if (i >= COUT * CIN * KW) return;
    int co  = i / (CIN * KW);
    int rem = i - co * (CIN * KW);
    int ci  = rem / KW;
    int k   = rem - ci * KW;
    uint u = __float_as_uint(W[i]);
    uint r = (u + 0x7FFFu + ((u >> 16) & 1u)) >> 16;   // RNE to bf16
    Wt[(k * COUT + co) * CIN + ci] = (ushort)r;
}

// Fused: BN -> sign -> conv (bf16 MFMA) -> alpha -> PReLU -> maxpool2.
// R4 — concurrency, not schedule. Evidence R0/R1/R3: dur tracks resident
// blocks (5/5/4 by LDS -> 87/84/100us), insensitive to barrier micro-
// structure; all pipes <=25% => latency-bound, and grid=1024 caps the CU
// at 4 blocks TOTAL (no replacements). Change: NT 4->2 => 2048 blocks =
// 8/CU with 5 resident (LDS 29696B) -> one block's prologue/DMA overlaps
// another's k-loop (inter-block de-lockstep, free). Inner structure is
// R1's proven best verbatim: swizzled stg (conflicts 4x down), W-register
// rotation, 2 barriers/t.
__global__ __launch_bounds__(256, 3)
void conv_kernel(const float* __restrict__ I,
                 const float* __restrict__ bn_g, const float* __restrict__ bn_b,
                 const float* __restrict__ bn_m, const float* __restrict__ bn_v,
                 const ushort* __restrict__ Wt,
                 const float* __restrict__ alpha, const float* __restrict__ prelu,
                 float* __restrict__ out) {
    __shared__ __attribute__((aligned(16))) float  raw[CIN * RAWP];      // 20480 B
    __shared__ __attribute__((aligned(16))) ushort stg[RROWS * SPITCH];  // 9216 B

    int tid = threadIdx.x;
    int lane = tid & 63, wave = tid >> 6;
    int b = blockIdx.y, bx = blockIdx.x;
    int l0base = bx * (64 * NT);

    const float* Ib = I + (size_t)b * CIN * LEN;

    // DMA plan: slot s = wave*5+i covers chunks n = s*64+lane; chunk n = ci*20+c
    // lands at raw float index n*4 = ci*80 + 4c; global p = l0-8+4c+(0..3).
    const char* gb[5]; int cb[5];
    #pragma unroll
    for (int i = 0; i < 5; ++i) {
        int n = (wave * 5 + i) * 64 + lane;
        int ci = n / 20;
        int c  = n - 20 * ci;
        cb[i] = 16 * c - 32;                                  // byte offset before +4*l0
        gb[i] = (const char*)(Ib + (size_t)ci * LEN) + cb[i];
    }

    {   // DMA tile 0
        int l4 = 4 * l0base;
        #pragma unroll
        for (int i = 0; i < 5; ++i) {
            int off = cb[i] + l4;
            if (off >= 0 && off + 16 <= LEN * 4)
                __builtin_amdgcn_global_load_lds((gp1_t)(gb[i] + l4),
                                                 (lp3_t)(raw + (wave * 5 + i) * 256), 16, 0, 0);
        }
    }

    // ---- per-thread BN consts (t-invariant): tid<144 owns ci 8*(tid&7)+.. ----
    int brq  = tid >> 3;        // p-quad row group, active < 18
    int bg8  = tid & 7;         // ci chunk
    int bci0 = bg8 * 8;
    float sc[8], mn[8], bt[8];
    if (tid < 144) {
        #pragma unroll
        for (int c = 0; c < 8; ++c) {
            int ci = bci0 + c;
            // bit-exact vs np fp32: gamma / sqrt(var + eps)
            sc[c] = __fdiv_rn(bn_g[ci], __fsqrt_rn(__fadd_rn(bn_v[ci], 1e-5f)));
            mn[c] = bn_m[ci];
            bt[c] = bn_b[ci];
        }
    }

    int quad = lane >> 4, lr = lane & 15;
    int cout0 = wave * 32;
    const ushort* wbase = Wt + ((size_t)cout0 + lr) * CIN + quad * 8;
    float pw  = prelu[0];
    float al0 = alpha[cout0 + lr];
    float al1 = alpha[cout0 + 16 + lr];
    float* obase = out + ((size_t)b * COUT) * LPOOL + bx * (32 * NT);

    // W k=0 preload (t-invariant; rotation keeps steady state across t)
    v8bf c00 = *(const v8bf*)(wbase);
    v8bf c01 = *(const v8bf*)(wbase + 16 * CIN);
    v8bf c10 = *(const v8bf*)(wbase + 32);
    v8bf c11 = *(const v8bf*)(wbase + 32 + 16 * CIN);

    __syncthreads();   // DMA(0) drained (vmcnt(0) at barrier)

    const float4* raw4 = (const float4*)raw;

    for (int t = 0; t < NT; ++t) {
        int l0 = l0base + t * 64;

        // ---- binarize raw -> stg (vectorized, swizzled writes) ----
        if (tid < 144) {
            float4 fr[8];
            #pragma unroll
            for (int c = 0; c < 8; ++c)
                fr[c] = raw4[(bci0 + c) * (RAWP / 4) + brq + 1];
            #pragma unroll
            for (int j = 0; j < 4; ++j) {
                int r = 4 * brq + j;
                int p = l0 - 4 + r;
                bool pok = (p >= 0) && (p < LEN);
                v8us u;
                #pragma unroll
                for (int c = 0; c < 8; ++c) {
                    float v = ((const float*)&fr[c])[j];
                    // (v - mean) * scale + beta, exact np rounding (sign boundary)
                    float x = __fadd_rn(__fmul_rn(__fsub_rn(v, mn[c]), sc[c]), bt[c]);
                    ushort s = x > 0.f ? (ushort)0x3F80 : (x < 0.f ? (ushort)0xBF80 : (ushort)0);
                    u[c] = pok ? s : (ushort)0;
                }
                *(v8us*)(&stg[r * SPITCH + ((bg8 ^ (r & 7)) << 3)]) = u;
            }
        }
        __syncthreads();   // stg visible; raw free for next DMA

        if (t + 1 < NT) {  // DMA(t+1) flies under MFMA(t)
            int l4 = 4 * (l0 + 64);
            #pragma unroll
            for (int i = 0; i < 5; ++i) {
                int off = cb[i] + l4;
                if (off >= 0 && off + 16 <= LEN * 4)
                    __builtin_amdgcn_global_load_lds((gp1_t)(gb[i] + l4),
                                                     (lp3_t)(raw + (wave * 5 + i) * 256), 16, 0, 0);
            }
        }

        // ---- MFMA(t): k-loop unroll 1, W double-buffered in regs ----
        v4f acc[4][2];
        #pragma unroll
        for (int mt = 0; mt < 4; ++mt) { acc[mt][0] = (v4f)0.f; acc[mt][1] = (v4f)0.f; }

        #pragma unroll 1
        for (int k = 0; k < KW; ++k) {
            // prefetch next tap's W (k=6 wraps to k=0 for next t)
            int nk = (k == KW - 1) ? 0 : k + 1;
            const ushort* wn = wbase + nk * COUT * CIN;
            v8bf n00 = *(const v8bf*)(wn);
            v8bf n01 = *(const v8bf*)(wn + 16 * CIN);
            v8bf n10 = *(const v8bf*)(wn + 32);
            v8bf n11 = *(const v8bf*)(wn + 32 + 16 * CIN);

            // A row for output l=mt*16+lr at tap k: r = l + k + 1; (r&7) mt-invariant
            int rk = lr + 1 + k;
            int s8 = rk & 7;
            const ushort* a0p = &stg[rk * SPITCH + ((quad ^ s8) << 3)];        // ci 0..31
            const ushort* a1p = &stg[rk * SPITCH + (((quad ^ 4) ^ s8) << 3)];  // ci 32..63
            #pragma unroll
            for (int mt = 0; mt < 4; ++mt) {
                v8bf a0 = *(const v8bf*)(a0p + mt * 16 * SPITCH);
                v8bf a1 = *(const v8bf*)(a1p + mt * 16 * SPITCH);
                acc[mt][0] = __builtin_amdgcn_mfma_f32_16x16x32_bf16(a0, c00, acc[mt][0], 0, 0, 0);
                acc[mt][1] = __builtin_amdgcn_mfma_f32_16x16x32_bf16(a0, c01, acc[mt][1], 0, 0, 0);
                acc[mt][0] = __builtin_amdgcn_mfma_f32_16x16x32_bf16(a1, c10, acc[mt][0], 0, 0, 0);
                acc[mt][1] = __builtin_amdgcn_mfma_f32_16x16x32_bf16(a1, c11, acc[mt][1], 0, 0, 0);
            }
            c00 = n00; c01 = n01; c10 = n10; c11 = n11;   // rotate
        }

        // ---- epilogue(t): alpha * PReLU, in-lane pool, float2 stores ----
        float* ob = obase + t * 32;
        #pragma unroll
        for (int n2 = 0; n2 < 2; ++n2) {
            float al = n2 ? al1 : al0;
            int co = cout0 + n2 * 16 + lr;
            float* oc = ob + (size_t)co * LPOOL + quad * 2;
            #pragma unroll
            for (int mt = 0; mt < 4; ++mt) {
                float v0 = acc[mt][n2][0] * al; v0 = v0 > 0.f ? v0 : pw * v0;
                float v1 = acc[mt][n2][1] * al; v1 = v1 > 0.f ? v1 : pw * v1;
                float v2 = acc[mt][n2][2] * al; v2 = v2 > 0.f ? v2 : pw * v2;
                float v3 = acc[mt][n2][3] * al; v3 = v3 > 0.f ? v3 : pw * v3;
                *(float2*)(oc + mt * 8) = make_float2(fmaxf(v0, v1), fmaxf(v2, v3));
            }
        }
        __syncthreads();   // drains DMA(t+1); protects stg until MFMA done
    }
}

extern "C" void kernel_launch(void* const* d_in, const int* in_sizes, int n_in,
                              void* d_out, int out_size, void* d_ws, size_t ws_size,
                              hipStream_t stream) {
    const float* I      = (const float*)d_in[0];
    const float* bn_g   = (const float*)d_in[1];
    const float* bn_b   = (const float*)d_in[2];
    const float* bn_m   = (const float*)d_in[3];
    const float* bn_v   = (const float*)d_in[4];
    const float* conv_w = (const float*)d_in[5];
    const float* alpha  = (const float*)d_in[6];
    const float* prelu  = (const float*)d_in[7];
    float* out = (float*)d_out;

    ushort* Wt = (ushort*)d_ws;   // 7*128*64*2 = 114688 bytes

    wconv_kernel<<<(COUT * CIN * KW + 255) / 256, 256, 0, stream>>>(conv_w, Wt);
    dim3 grid(LEN / (64 * NT), BATCH);
    conv_kernel<<<grid, 256, 0, stream>>>(I, bn_g, bn_b, bn_m, bn_v, Wt, alpha, prelu, out);
}

// Round 6
// 179.092 us; speedup vs baseline: 1.0685x; 1.0015x over previous
//
#include <hip/hip_runtime.h>
#include <hip/hip_bf16.h>
#include <stdint.h>

#define BATCH 64
#define CIN   64
#define LEN   4096
#define COUT  128
#define KW    7
#define LPOOL 2048
#define NT    4     // l sub-tiles of 64 per block
#define RROWS 72    // sign rows: p = l0-4+r, r in [0,72)
#define RAWP  80    // raw floats per ci row: p = l0-8+col, col in [0,80)
#define SPITCH 64   // ushorts per stg row = 128B (XOR-swizzled by (r&7)<<4 bytes)

typedef __bf16 v8bf __attribute__((ext_vector_type(8)));
typedef unsigned short v8us __attribute__((ext_vector_type(8)));
typedef float  v4f  __attribute__((ext_vector_type(4)));

typedef const __attribute__((address_space(1))) void* gp1_t;
typedef __attribute__((address_space(3))) void* lp3_t;

// Convert conv_w [COUT][CIN][KW] fp32 -> Wt [KW][COUT][CIN] bf16 (RNE).
__global__ __launch_bounds__(256)
void wconv_kernel(const float* __restrict__ W, ushort* __restrict__ Wt) {
    int i = blockIdx.x * 256 + threadIdx.x;
    if (i >= COUT * CIN * KW) return;
    int co  = i / (CIN * KW);
    int rem = i - co * (CIN * KW);
    int ci  = rem / KW;
    int k   = rem - ci * KW;
    uint u = __float_as_uint(W[i]);
    uint r = (u + 0x7FFFu + ((u >> 16) & 1u)) >> 16;   // RNE to bf16
    Wt[(k * COUT + co) * CIN + ci] = (ushort)r;
}

// lgkm-only barrier: producer->consumer for LDS WITHOUT draining vmcnt
// (stores / async DMA stay in flight across it).
static __device__ __forceinline__ void sync_lds() {
    asm volatile("s_waitcnt lgkmcnt(0)" ::: "memory");
    __builtin_amdgcn_s_barrier();
}
static __device__ __forceinline__ void wait_vm0() {
    asm volatile("s_waitcnt vmcnt(0)" ::: "memory");
}

// Fused: BN -> sign -> conv (bf16 MFMA) -> alpha -> PReLU -> maxpool2.
// R6 — disentangle vmcnt. Diagnosis: m97's GEMM K-loop has the same
// per-iter mix (8 ds_read_b128 + 2 glds + 16 MFMA, 2 barriers) at 37%
// MfmaUtil; we sit at 13.7%. Difference: our in-loop VMEM is W->VGPR
// loads, so every rotation wait is a FIFO vmcnt(0) that drains the async
// raw-DMA issued before the k-loop (k=0: full HBM latency, every phase)
// and every __syncthreads drains fresh epilogue stores. Changes:
//  (1) wave-private DMA (R3 plan, verified): raw needs only own-wave
//      vmcnt, never a barrier drain.
//  (2) DMA(t+1) + stores(t) issue AFTER kloop(t): during the k-loop the
//      only outstanding VMEM is W -> rotation waits are counted W-only,
//      covered by the 16 MFMAs.
//  (3) both barriers lgkm-only (raw s_barrier): no barrier ever drains
//      vmcnt. stg single-buffered (LDS 29696B, 5 blocks), WAR-protected
//      by barrier #1.
// Per t: kloop | DMA(t+1) | pool | stores | lgkm-bar | wvm0 |
//        binarize(t+1) | lgkm-bar.
// launch_bounds (256,4): pin unified regs <=128 (4 waves/SIMD bracket —
// VGPR_Count 60 excludes ~32 acc AGPRs; unified ~92-96 caps us at 16
// waves/CU, which matches all measured occupancy).
__global__ __launch_bounds__(256, 4)
void conv_kernel(const float* __restrict__ I,
                 const float* __restrict__ bn_g, const float* __restrict__ bn_b,
                 const float* __restrict__ bn_m, const float* __restrict__ bn_v,
                 const ushort* __restrict__ Wt,
                 const float* __restrict__ alpha, const float* __restrict__ prelu,
                 float* __restrict__ out) {
    __shared__ __attribute__((aligned(16))) float  raw[CIN * RAWP];      // 20480 B, wave-private quarters
    __shared__ __attribute__((aligned(16))) ushort stg[RROWS * SPITCH];  // 9216 B

    int tid = threadIdx.x;
    int lane = tid & 63, wave = tid >> 6;
    int b = blockIdx.y, bx = blockIdx.x;
    int l0base = bx * (64 * NT);

    const float* Ib = I + (size_t)b * CIN * LEN;

    // Wave-private DMA plan (R3, verified): wave w owns ci [16w,16w+16) =
    // 320 float4 chunks = 5 slots x 64 lanes. Chunk m = i*64+lane =
    // cil*20 + c lands at rawb float m*4 (HW: uniform base rawb+i*256 +
    // lane*16B); global p = l0-8+4c+(0..3).
    float* rawb = raw + wave * 1280;
    const char* gb[5]; int cb[5];
    #pragma unroll
    for (int i = 0; i < 5; ++i) {
        int m = i * 64 + lane;
        int cil = m / 20;
        int c   = m - 20 * cil;
        cb[i] = 16 * c - 32;                                  // byte offset before +4*l0
        gb[i] = (const char*)(Ib + (size_t)(16 * wave + cil) * LEN) + cb[i];
    }

    auto dma_tile = [&](int l0t) {
        int l4 = 4 * l0t;
        #pragma unroll
        for (int i = 0; i < 5; ++i) {
            int off = cb[i] + l4;
            if (off >= 0 && off + 16 <= LEN * 4)
                __builtin_amdgcn_global_load_lds((gp1_t)(gb[i] + l4),
                                                 (lp3_t)(rawb + i * 256), 16, 0, 0);
        }
    };

    dma_tile(l0base);            // DMA(0); raw single-buffered, one DMA in flight

    // ---- per-lane BN consts (t-invariant): lanes<36 of each wave handle
    // the wave's two ci-octets (g8 = 2*wave + (lane&1)) at row-quad lane>>1.
    int oc  = lane & 1;
    int brq = lane >> 1;              // 0..17 for lanes 0..35
    int g8  = 2 * wave + oc;
    float sc[8], mn[8], bt[8];
    if (lane < 36) {
        #pragma unroll
        for (int c = 0; c < 8; ++c) {
            int ci = 8 * g8 + c;
            // bit-exact vs np fp32: gamma / sqrt(var + eps)
            sc[c] = __fdiv_rn(bn_g[ci], __fsqrt_rn(__fadd_rn(bn_v[ci], 1e-5f)));
            mn[c] = bn_m[ci];
            bt[c] = bn_b[ci];
        }
    }

    int quad = lane >> 4, lr = lane & 15;
    int cout0 = wave * 32;
    const ushort* wbase = Wt + ((size_t)cout0 + lr) * CIN + quad * 8;
    float pw  = prelu[0];
    float al0 = alpha[cout0 + lr];
    float al1 = alpha[cout0 + 16 + lr];
    float* obase = out + ((size_t)b * COUT) * LPOOL + bx * (32 * NT);

    // W k=0 preload (t-invariant; rotation keeps steady state across t)
    v8bf c00 = *(const v8bf*)(wbase);
    v8bf c01 = *(const v8bf*)(wbase + 16 * CIN);
    v8bf c10 = *(const v8bf*)(wbase + 32);
    v8bf c11 = *(const v8bf*)(wbase + 32 + 16 * CIN);

    // binarize(tile): wave-private raw -> stg. Caller guarantees this
    // wave's DMA for the tile has drained (wait_vm0) before calling.
    auto binarize = [&](int l0t) {
        if (lane < 36) {
            const float4* r4 = (const float4*)rawb;
            float4 fr[8];
            #pragma unroll
            for (int c = 0; c < 8; ++c)
                fr[c] = r4[(8 * oc + c) * 20 + brq + 1];
            #pragma unroll
            for (int j = 0; j < 4; ++j) {
                int r = 4 * brq + j;
                int p = l0t - 4 + r;
                bool pok = (p >= 0) && (p < LEN);
                v8us u;
                #pragma unroll
                for (int c = 0; c < 8; ++c) {
                    float v = ((const float*)&fr[c])[j];
                    // (v - mean) * scale + beta, exact np rounding (sign boundary)
                    float x = __fadd_rn(__fmul_rn(__fsub_rn(v, mn[c]), sc[c]), bt[c]);
                    ushort s = x > 0.f ? (ushort)0x3F80 : (x < 0.f ? (ushort)0xBF80 : (ushort)0);
                    u[c] = pok ? s : (ushort)0;
                }
                *(v8us*)(&stg[r * SPITCH + ((g8 ^ (r & 7)) << 3)]) = u;
            }
        }
    };

    wait_vm0();                 // own DMA(0) + const loads landed
    binarize(l0base);           // consume raw(0); raw now free
    sync_lds();                 // stg(0) visible to all waves

    for (int t = 0; t < NT; ++t) {
        int l0 = l0base + t * 64;

        // ---- MFMA(t): only W-loads outstanding during the k-loop ----
        v4f acc[4][2];
        #pragma unroll
        for (int mt = 0; mt < 4; ++mt) { acc[mt][0] = (v4f)0.f; acc[mt][1] = (v4f)0.f; }

        #pragma unroll 1
        for (int k = 0; k < KW; ++k) {
            // prefetch next tap's W (k=6 wraps to k=0 for next t)
            int nk = (k == KW - 1) ? 0 : k + 1;
            const ushort* wn = wbase + nk * COUT * CIN;
            v8bf n00 = *(const v8bf*)(wn);
            v8bf n01 = *(const v8bf*)(wn + 16 * CIN);
            v8bf n10 = *(const v8bf*)(wn + 32);
            v8bf n11 = *(const v8bf*)(wn + 32 + 16 * CIN);

            // A row for output l=mt*16+lr at tap k: r = l + k + 1; (r&7) mt-invariant
            int rk = lr + 1 + k;
            int s8 = rk & 7;
            const ushort* a0p = &stg[rk * SPITCH + ((quad ^ s8) << 3)];        // ci 0..31
            const ushort* a1p = &stg[rk * SPITCH + (((quad ^ 4) ^ s8) << 3)];  // ci 32..63
            #pragma unroll
            for (int mt = 0; mt < 4; ++mt) {
                v8bf a0 = *(const v8bf*)(a0p + mt * 16 * SPITCH);
                v8bf a1 = *(const v8bf*)(a1p + mt * 16 * SPITCH);
                acc[mt][0] = __builtin_amdgcn_mfma_f32_16x16x32_bf16(a0, c00, acc[mt][0], 0, 0, 0);
                acc[mt][1] = __builtin_amdgcn_mfma_f32_16x16x32_bf16(a0, c01, acc[mt][1], 0, 0, 0);
                acc[mt][0] = __builtin_amdgcn_mfma_f32_16x16x32_bf16(a1, c10, acc[mt][0], 0, 0, 0);
                acc[mt][1] = __builtin_amdgcn_mfma_f32_16x16x32_bf16(a1, c11, acc[mt][1], 0, 0, 0);
            }
            c00 = n00; c01 = n01; c10 = n10; c11 = n11;   // rotate (W-only wait)
        }

        // ---- DMA(t+1): issued now, drains at next iter's wait_vm0 ----
        if (t + 1 < NT) dma_tile(l0 + 64);

        // ---- pool-compute: acc -> pooled pv, then stores ----
        float pv[2][4][2];
        #pragma unroll
        for (int n2 = 0; n2 < 2; ++n2) {
            float al = n2 ? al1 : al0;
            #pragma unroll
            for (int mt = 0; mt < 4; ++mt) {
                float v0 = acc[mt][n2][0] * al; v0 = v0 > 0.f ? v0 : pw * v0;
                float v1 = acc[mt][n2][1] * al; v1 = v1 > 0.f ? v1 : pw * v1;
                float v2 = acc[mt][n2][2] * al; v2 = v2 > 0.f ? v2 : pw * v2;
                float v3 = acc[mt][n2][3] * al; v3 = v3 > 0.f ? v3 : pw * v3;
                pv[n2][mt][0] = fmaxf(v0, v1);
                pv[n2][mt][1] = fmaxf(v2, v3);
            }
        }
        float* ob = obase + t * 32;
        #pragma unroll
        for (int n2 = 0; n2 < 2; ++n2) {
            int co = cout0 + n2 * 16 + lr;
            float* ocp = ob + (size_t)co * LPOOL + quad * 2;
            #pragma unroll
            for (int mt = 0; mt < 4; ++mt)
                *(float2*)(ocp + mt * 8) = make_float2(pv[n2][mt][0], pv[n2][mt][1]);
        }

        if (t + 1 < NT) {
            sync_lds();         // all waves done reading stg(t); no vmcnt drain
            wait_vm0();         // own DMA(t+1) (~stores+barrier old) + old stores
            binarize(l0 + 64);  // stg(t+1); raw free again
            sync_lds();         // stg(t+1) visible; stores stay in flight
        }
    }
}

extern "C" void kernel_launch(void* const* d_in, const int* in_sizes, int n_in,
                              void* d_out, int out_size, void* d_ws, size_t ws_size,
                              hipStream_t stream) {
    const float* I      = (const float*)d_in[0];
    const float* bn_g   = (const float*)d_in[1];
    const float* bn_b   = (const float*)d_in[2];
    const float* bn_m   = (const float*)d_in[3];
    const float* bn_v   = (const float*)d_in[4];
    const float* conv_w = (const float*)d_in[5];
    const float* alpha  = (const float*)d_in[6];
    const float* prelu  = (const float*)d_in[7];
    float* out = (float*)d_out;

    ushort* Wt = (ushort*)d_ws;   // 7*128*64*2 = 114688 bytes

    wconv_kernel<<<(COUT * CIN * KW + 255) / 256, 256, 0, stream>>>(conv_w, Wt);
    dim3 grid(LEN / (64 * NT), BATCH);
    conv_kernel<<<grid, 256, 0, stream>>>(I, bn_g, bn_b, bn_m, bn_v, Wt, alpha, prelu, out);
}